// Round 6
// baseline (5582.336 us; speedup 1.0000x reference)
//
#include <hip/hip_runtime.h>

typedef unsigned short ushort_t;
typedef unsigned long long u64_t;
typedef __attribute__((ext_vector_type(8))) short short8;
typedef __attribute__((ext_vector_type(4))) short short4v;
typedef __attribute__((ext_vector_type(4))) float floatx4;

// Problem constants: V=50000, E=512, H=512, L=32, B=64, T=512
// Chunked: NC=8 chunks of CS=64 steps.

__device__ __forceinline__ float bf2f(ushort_t u) {
  unsigned x = ((unsigned)u) << 16;
  return __builtin_bit_cast(float, x);
}
__device__ __forceinline__ ushort_t f2bf(float f) {
  unsigned x = __builtin_bit_cast(unsigned, f);
  x += 0x7FFFu + ((x >> 16) & 1u);
  return (ushort_t)(x >> 16);
}
__device__ __forceinline__ float sigf(float x) { return 1.0f / (1.0f + __expf(-x)); }
__device__ __forceinline__ float tanhf_(float x) { return 1.0f - 2.0f / (__expf(2.0f * x) + 1.0f); }

// ---------------- workspace layout (bytes) ----------------
static const size_t OFF_A    = 0;            // x_bf [32768][512] bf16 (32MB) + xgB0 pair (32MB)
                                             // out1 [32768][1024] bf16 (phases 3-4)   67108864
static const size_t OFF_OUT0 = 67108864;     // out0 [32768][1024] bf16                      67108864
static const size_t OFF_XG   = 134217728;    // xgA pair [64][64][2048] bf16 each (33554432)
                                             // emis [32768][32] f32 aliases this in phase 4
static const size_t OFF_WIH0 = 167772160;    // wih0_bf [2][2048][512] bf16    4194304
static const size_t OFF_WIH1 = 171966464;    // wih1_bf [2][2048][1024] bf16   8388608
static const size_t OFF_BIAS = 180355072;    // bias [2][2][2048] f32          32768
static const size_t OFF_WOUT = 180387840;    // w_out frag-major bf16          65536
static const size_t OFF_HC   = 180453376;    // h exchange [2 layers][2 dir][2 buf][32768] bf16 frag-major
static const size_t OFF_CST  = 181501952;    // c state [2 layers][2 dir][64][512] f32        524288
static const size_t OFF_BAR  = 182026240;    // wave flags [2 layer][2 dir][32 g][4 w][16] int  32768
static const size_t OFF_NUM  = 182059008;    // (spare)                        256
static const size_t OFF_PERB = 182059264;    // perb[64] f32                   256
static const size_t OFF_END  = 182059520;
// if ws_size >= OFF_END + 33554432: xgB1 pair lives at OFF_END (layer-1 overlap)

// ---------------- prep + embed fused ----------------
__global__ void prep_embed(const int* __restrict__ datas, const float* __restrict__ emb,
                           ushort_t* __restrict__ x_bf,
                           const float* __restrict__ w_ih0, const float* __restrict__ w_ih1,
                           const float* __restrict__ b_ih, const float* __restrict__ b_hh,
                           const float* __restrict__ w_out,
                           ushort_t* __restrict__ wih0_bf, ushort_t* __restrict__ wih1_bf,
                           float* __restrict__ bias, ushort_t* __restrict__ wout_bf) {
  int idx = blockIdx.x * 256 + threadIdx.x;
  int stride = gridDim.x * 256;
  // embedding gather + cast (2097152 = 32768 rows * 64 subs)
  for (int i = idx; i < 2097152; i += stride) {
    int row = i >> 6, sub = i & 63;
    int tok = datas[row];
    const float4* ep = (const float4*)(emb + (size_t)tok * 512 + sub * 8);
    float4 f0 = ep[0], f1 = ep[1];
    short8 v;
    v[0] = (short)f2bf(f0.x); v[1] = (short)f2bf(f0.y);
    v[2] = (short)f2bf(f0.z); v[3] = (short)f2bf(f0.w);
    v[4] = (short)f2bf(f1.x); v[5] = (short)f2bf(f1.y);
    v[6] = (short)f2bf(f1.z); v[7] = (short)f2bf(f1.w);
    *(short8*)(x_bf + (size_t)row * 512 + sub * 8) = v;
  }
  for (int i = idx; i < 2097152; i += stride) wih0_bf[i] = f2bf(w_ih0[i]);
  for (int i = idx; i < 4194304; i += stride) wih1_bf[i] = f2bf(w_ih1[i]);
  for (int i = idx; i < 8192; i += stride) bias[i] = b_ih[i] + b_hh[i];
  // w_out [1024][32] -> 16x16x32 B-operand frag-major
  for (int i = idx; i < 32768; i += stride) {
    int j = i & 7, Ls = (i >> 3) & 63, kb = (i >> 9) & 31, nt = i >> 14;
    int n = nt * 16 + (Ls & 15);
    int k = kb * 32 + ((Ls >> 4) & 3) * 8 + j;
    wout_bf[i] = f2bf(w_out[k * 32 + n]);
  }
}

// ---------------- GEMM body (chunked input-projection) ----------------
// xg layout: [t*64+b][col*4 + q] (gate-INNER) so the lstm reads one step's 4 gate
// values per (row,col) with a single 8B load.
__device__ __forceinline__ void gemm_body(ushort_t* alds, ushort_t* blds, int gid, int tid,
                                          const ushort_t* __restrict__ A, int K,
                                          const ushort_t* __restrict__ W,
                                          const float* __restrict__ biasL,
                                          ushort_t* __restrict__ xg0,
                                          ushort_t* __restrict__ xg1,
                                          int t00, int t01) {
  int dir = gid >> 9, r = gid & 511;
  int mt = r & 31, ntt = r >> 5;
  int t0 = dir ? t01 : t00;
  const ushort_t* Bm = W + (size_t)dir * 2048 * K;
  const float* bptr = biasL + dir * 2048;
  ushort_t* xg = dir ? xg1 : xg0;
  int bm0 = mt * 128, bn0 = ntt * 128;
  int L = tid & 63, w = tid >> 6;
  int wm = w & 1, wn = w >> 1;
  floatx4 acc[4][4] = {};
  for (int k0 = 0; k0 < K; k0 += 32) {
    __syncthreads();
    #pragma unroll
    for (int rep = 0; rep < 2; rep++) {
      int slot = rep * 256 + tid;  // 0..511
      int t8 = slot >> 6, Ls = slot & 63;
      int col = k0 + (Ls >> 4) * 8;
      int mp = bm0 + t8 * 16 + (Ls & 15);                 // m' in [0,4096)
      int Arow = (mp >> 6) * 512 + t0 + (mp & 63);        // b*512 + t
      *(short8*)&alds[slot * 8] = *(const short8*)&A[(size_t)Arow * K + col];
      int rowb = bn0 + t8 * 16 + (Ls & 15);               // gate col in [0,2048)
      *(short8*)&blds[slot * 8] = *(const short8*)&Bm[(size_t)rowb * K + col];
    }
    __syncthreads();
    short8 af[4];
    #pragma unroll
    for (int a = 0; a < 4; a++) af[a] = *(const short8*)&alds[((wm * 4 + a) * 64 + L) * 8];
    #pragma unroll
    for (int bq = 0; bq < 4; bq++) {
      short8 bfr = *(const short8*)&blds[((wn * 4 + bq) * 64 + L) * 8];
      #pragma unroll
      for (int a = 0; a < 4; a++)
        acc[a][bq] = __builtin_amdgcn_mfma_f32_16x16x32_bf16(af[a], bfr, acc[a][bq], 0, 0, 0);
    }
  }
  int lm = L >> 4, ln = L & 15;
  #pragma unroll
  for (int bq = 0; bq < 4; bq++) {
    int n = bn0 + (wn * 4 + bq) * 16 + ln;  // [0,2048) gate-major
    float bv = bptr[n];
    int nidx = ((n & 511) << 2) + (n >> 9);  // gate-inner permutation
    #pragma unroll
    for (int a = 0; a < 4; a++) {
      #pragma unroll
      for (int rr = 0; rr < 4; rr++) {
        int m = bm0 + (wm * 4 + a) * 16 + lm * 4 + rr;
        int b = m >> 6, ts = m & 63;
        xg[((size_t)(ts * 64 + b)) * 2048 + nidx] = f2bf(acc[a][bq][rr] + bv);
      }
    }
  }
}

__global__ __launch_bounds__(256) void gemm_chunk(const ushort_t* __restrict__ A, int K,
                                                  const ushort_t* __restrict__ W,
                                                  const float* __restrict__ biasL,
                                                  ushort_t* __restrict__ xg0c,
                                                  ushort_t* __restrict__ xg1c,
                                                  int t00, int t01) {
  __shared__ alignas(16) ushort_t alds[512 * 8];
  __shared__ alignas(16) ushort_t blds[512 * 8];
  gemm_body(alds, blds, blockIdx.x, threadIdx.x, A, K, W, biasL, xg0c, xg1c, t00, t01);
}

// ---------------- LSTM body: one chunk of 64 steps (R1/R2 protocol + poll pipeline) ----------------
// block bid in [0,64): dir d = bid>>5, slice g = bid&31 owns h-cols [g*16,g*16+16).
// h exchanged frag-major at AGENT scope; per-WAVE sync planes. Per-step protocol:
//   h stores -> s_waitcnt vmcnt(0) (per-wave) -> lane0 posts wave-flag -> out/xg prefetch
//   fill the poll window -> 2-deep PIPELINED poll of the 32 same-plane wave-flags.
__device__ __forceinline__ void lstm_body(ushort_t* wlds, int bid, int tid,
                                          const ushort_t* __restrict__ xg0c,
                                          const ushort_t* __restrict__ xg1c,
                                          const float* __restrict__ whh_f,  // layer base [2][2048][512] f32
                                          ushort_t* __restrict__ hcL,       // [2 dir][2 buf][32768]
                                          float* __restrict__ cstL,         // [2 dir][64][512]
                                          ushort_t* __restrict__ outL,      // [32768][1024], col offset d*512
                                          int* __restrict__ barF, int c) {
  int d = bid >> 5, g = bid & 31, j0 = g * 16;
  int L = tid & 63, w = tid >> 6;
  const float* wptr = whh_f + (size_t)d * 2048 * 512;
  #pragma unroll
  for (int it = 0; it < 16; it++) {
    int slot = it * 256 + tid;  // 0..4095
    int q = slot >> 10, kb = (slot >> 6) & 15, Ls = slot & 63;
    int gcol = q * 512 + j0 + (Ls & 15);
    int k = kb * 32 + (Ls >> 4) * 8;
    const float* src = wptr + (size_t)gcol * 512 + k;
    float4 f0 = *(const float4*)src;
    float4 f1 = *(const float4*)(src + 4);
    short8 v;
    v[0] = (short)f2bf(f0.x); v[1] = (short)f2bf(f0.y);
    v[2] = (short)f2bf(f0.z); v[3] = (short)f2bf(f0.w);
    v[4] = (short)f2bf(f1.x); v[5] = (short)f2bf(f1.y);
    v[6] = (short)f2bf(f1.z); v[7] = (short)f2bf(f1.w);
    *(short8*)&wlds[slot * 8] = v;
  }
  __syncthreads();
  const ushort_t* xgd = d ? xg1c : xg0c;
  ushort_t* hcd = hcL + (size_t)d * 2 * 32768;     // [2 parity][32768]
  int* flg = barF + d * 2048;                      // [32 g][4 w][16] ints (64B spacing)
  int* myflag = flg + (g * 4 + w) * 16;
  const int* pollp = flg + ((L & 31) * 4 + w) * 16;  // lane L<32 polls block L, wave w
  bool pact = (L < 32);
  int q8 = L >> 4, jj = L & 15;
  int mbase = w * 16 + q8 * 4;                  // C-layout batch-row base
  // writer slot (even-jj lanes store packed dwords for cols jj, jj+1):
  int wslot = ((w * 16 + (g >> 1)) * 64 + q8 * 4 + 16 * ((g & 1) * 2 + (jj >> 3))) * 8 + (jj & 7);
  // reader base: wave w, lane L, kb: 16B at ushort index rbase + kb*512
  int rbase = (w * 16 * 64 + L) * 8;
  float cv[4];
  #pragma unroll
  for (int rr = 0; rr < 4; rr++) cv[rr] = cstL[(size_t)d * 32768 + (mbase + rr) * 512 + j0 + jj];

  // xg gate-inner layout: one 8B load per (row,col) gives the 4 gate values
  auto ldxg = [&](int sl2, ushort_t dst[4][4]) {
    int ts2 = d ? (63 - sl2) : sl2;
    #pragma unroll
    for (int rr = 0; rr < 4; rr++) {
      const short4v* xrow = (const short4v*)(xgd + ((size_t)(ts2 * 64 + mbase + rr)) * 2048
                                             + ((j0 + jj) << 2));
      short4v v = *xrow;
      #pragma unroll
      for (int q = 0; q < 4; q++) dst[q][rr] = (ushort_t)v[q];
    }
  };

  ushort_t xgu[4][4];
  ldxg(0, xgu);

  for (int sl = 0; sl < 64; sl++) {
    int s = c * 64 + sl;
    int t = d ? (511 - s) : s;
    const u64_t* h64 = (const u64_t*)(hcd + (size_t)(s & 1) * 32768);
    unsigned* h32w = (unsigned*)(hcd + (size_t)((s + 1) & 1) * 32768);
    // ---- issue ALL h loads upfront (32 independent agent-scope u64 loads) ----
    int b64 = rbase >> 2;  // u64 index; kb adds 128
    u64_t hv[32];
    #pragma unroll
    for (int kb = 0; kb < 16; kb++) {
      hv[2 * kb]     = __hip_atomic_load(h64 + b64 + kb * 128,     __ATOMIC_RELAXED, __HIP_MEMORY_SCOPE_AGENT);
      hv[2 * kb + 1] = __hip_atomic_load(h64 + b64 + kb * 128 + 1, __ATOMIC_RELAXED, __HIP_MEMORY_SCOPE_AGENT);
    }
    floatx4 acc[4] = {};
    #pragma unroll
    for (int kb = 0; kb < 16; kb++) {
      union { u64_t u[2]; short8 v; } pk;
      pk.u[0] = hv[2 * kb];
      pk.u[1] = hv[2 * kb + 1];
      short8 a = pk.v;
      #pragma unroll
      for (int q = 0; q < 4; q++) {
        short8 bfr = *(const short8*)&wlds[((q * 16 + kb) * 64 + L) * 8];
        acc[q] = __builtin_amdgcn_mfma_f32_16x16x32_bf16(a, bfr, acc[q], 0, 0, 0);
      }
    }
    // ---- pointwise LSTM cell ----
    ushort_t hbv[4];
    #pragma unroll
    for (int rr = 0; rr < 4; rr++) {
      float ii = acc[0][rr] + bf2f(xgu[0][rr]);
      float ff = acc[1][rr] + bf2f(xgu[1][rr]);
      float gg = acc[2][rr] + bf2f(xgu[2][rr]);
      float oo = acc[3][rr] + bf2f(xgu[3][rr]);
      float cc = sigf(ff) * cv[rr] + sigf(ii) * tanhf_(gg);
      cv[rr] = cc;
      hbv[rr] = f2bf(sigf(oo) * tanhf_(cc));
    }
    // ---- pack column pairs (jj, jj^1) into dwords; even-jj lanes store h ONLY ----
    bool evn = (jj & 1) == 0;
    unsigned pk4[4];
    #pragma unroll
    for (int rr = 0; rr < 4; rr++) {
      unsigned mine = (unsigned)hbv[rr];
      unsigned nb = (unsigned)__shfl_xor((int)mine, 1, 64);
      pk4[rr] = mine | (nb << 16);
      if (evn)
        __hip_atomic_store(h32w + ((wslot + rr * 8) >> 1), pk4[rr],
                           __ATOMIC_RELAXED, __HIP_MEMORY_SCOPE_AGENT);
    }
    if (sl != 63) {
      // drain this wave's h stores (and retire its h loads) — per-wave counter
      asm volatile("s_waitcnt vmcnt(0)" ::: "memory");
      if (L == 0)
        __hip_atomic_store(myflag, s + 1, __ATOMIC_RELAXED, __HIP_MEMORY_SCOPE_AGENT);
      // ---- fill the poll window: out1 stores + next-step xg prefetch ----
      if (evn) {
        #pragma unroll
        for (int rr = 0; rr < 4; rr++) {
          int m = mbase + rr;
          *(unsigned*)&outL[((size_t)m * 512 + t) * 1024 + (d << 9) + j0 + jj] = pk4[rr];
        }
      }
      ldxg(sl + 1, xgu);
      // ---- 2-deep pipelined poll: keep one flag load in flight, check the previous ----
      int target = s + 1, guard = 0;
      int f0 = pact ? __hip_atomic_load(pollp, __ATOMIC_RELAXED, __HIP_MEMORY_SCOPE_AGENT)
                    : target;
      while (guard < (1 << 17)) {
        int f1 = pact ? __hip_atomic_load(pollp, __ATOMIC_RELAXED, __HIP_MEMORY_SCOPE_AGENT)
                      : target;
        if (__ballot(f0 >= target) == ~0ULL) break;
        f0 = f1;
        guard++;
      }
    } else {
      if (evn) {
        #pragma unroll
        for (int rr = 0; rr < 4; rr++) {
          int m = mbase + rr;
          *(unsigned*)&outL[((size_t)m * 512 + t) * 1024 + (d << 9) + j0 + jj] = pk4[rr];
        }
      }
    }
  }
  #pragma unroll
  for (int rr = 0; rr < 4; rr++) cstL[(size_t)d * 32768 + (mbase + rr) * 512 + j0 + jj] = cv[rr];
}

__global__ __launch_bounds__(256) void lstm_chunk(const ushort_t* __restrict__ xg0c,
                                                  const ushort_t* __restrict__ xg1c,
                                                  const float* __restrict__ whh_f,
                                                  ushort_t* __restrict__ hcL,
                                                  float* __restrict__ cstL,
                                                  ushort_t* __restrict__ outL,
                                                  int* __restrict__ barF, int c) {
  __shared__ alignas(16) ushort_t wlds[32768];  // 64 KB
  lstm_body(wlds, blockIdx.x, threadIdx.x, xg0c, xg1c, whh_f, hcL, cstL, outL, barF, c);
}

// ---------------- fused dispatch: lstm(c) on blocks 0..63  ||  gemm(c+1) on blocks 64..1087 ----
__global__ __launch_bounds__(256) void fused_chunk(
    // lstm(c) args
    const ushort_t* __restrict__ l_xg0, const ushort_t* __restrict__ l_xg1,
    const float* __restrict__ whh_f, ushort_t* __restrict__ hcL,
    float* __restrict__ cstL, ushort_t* __restrict__ outL,
    int* __restrict__ barF, int c,
    // gemm(c+1) args
    const ushort_t* __restrict__ g_A, int g_K,
    const ushort_t* __restrict__ g_W, const float* __restrict__ g_bias,
    ushort_t* __restrict__ g_xg0, ushort_t* __restrict__ g_xg1,
    int g_t00, int g_t01) {
  __shared__ alignas(16) ushort_t lds[32768];  // 64 KB, unioned
  if (blockIdx.x < 64) {
    lstm_body(lds, blockIdx.x, threadIdx.x, l_xg0, l_xg1, whh_f, hcL, cstL, outL, barF, c);
  } else {
    gemm_body(lds, lds + 4096, blockIdx.x - 64, threadIdx.x,
              g_A, g_K, g_W, g_bias, g_xg0, g_xg1, g_t00, g_t01);
  }
}

// ---------------- emissions: [32768,1024] @ [1024,32] + b_out ----------------
__global__ __launch_bounds__(256) void emis_kernel(const ushort_t* __restrict__ out1,
                                                   const ushort_t* __restrict__ wout_bf,
                                                   const float* __restrict__ b_out,
                                                   float* __restrict__ emis) {
  int tid = threadIdx.x, L = tid & 63, w = tid >> 6;
  int bm0 = blockIdx.x * 128;
  int q8 = L >> 4, ln = L & 15;
  floatx4 acc[2][2] = {};
  #pragma unroll 4
  for (int kb = 0; kb < 32; kb++) {
    short8 a0 = *(const short8*)&out1[(size_t)(bm0 + (w * 2 + 0) * 16 + ln) * 1024 + kb * 32 + q8 * 8];
    short8 a1 = *(const short8*)&out1[(size_t)(bm0 + (w * 2 + 1) * 16 + ln) * 1024 + kb * 32 + q8 * 8];
    #pragma unroll
    for (int nt = 0; nt < 2; nt++) {
      short8 bfr = *(const short8*)&wout_bf[((size_t)(nt * 32 + kb) * 64 + L) * 8];
      acc[0][nt] = __builtin_amdgcn_mfma_f32_16x16x32_bf16(a0, bfr, acc[0][nt], 0, 0, 0);
      acc[1][nt] = __builtin_amdgcn_mfma_f32_16x16x32_bf16(a1, bfr, acc[1][nt], 0, 0, 0);
    }
  }
  #pragma unroll
  for (int mt = 0; mt < 2; mt++) {
    #pragma unroll
    for (int nt = 0; nt < 2; nt++) {
      int n = nt * 16 + ln;
      float bv = b_out[n];
      #pragma unroll
      for (int rr = 0; rr < 4; rr++) {
        int m = bm0 + (w * 2 + mt) * 16 + q8 * 4 + rr;
        emis[(size_t)m * 32 + n] = acc[mt][nt][rr] + bv;
      }
    }
  }
}

// ---------------- CRF forward scan (numerator folded in) ----------------
__global__ __launch_bounds__(64) void fwd_kernel(const int* __restrict__ labels,
                                                 const float* __restrict__ emis,
                                                 const float* __restrict__ trans,
                                                 const float* __restrict__ cstart,
                                                 const float* __restrict__ cend,
                                                 float* __restrict__ perb) {
  int b = blockIdx.x, tid = threadIdx.x, j = tid & 31;
  // numerator (butterfly reduce -> all lanes hold the sum)
  float sn = 0.f;
  for (int t = tid; t < 512; t += 64) {
    int tag = labels[b * 512 + t];
    sn += emis[(size_t)(b * 512 + t) * 32 + tag];
    if (t < 511) sn += trans[tag * 32 + labels[b * 512 + t + 1]];
  }
  #pragma unroll
  for (int off = 32; off > 0; off >>= 1) sn += __shfl_xor(sn, off, 64);
  sn += cstart[labels[b * 512]] + cend[labels[b * 512 + 511]];
  // forward scan
  float etr[32];
  #pragma unroll
  for (int i = 0; i < 32; i++) etr[i] = __expf(trans[i * 32 + j]);
  float alpha = cstart[j] + emis[(size_t)(b * 512) * 32 + j];
  float e_cur = emis[(size_t)(b * 512 + 1) * 32 + j];
  for (int t = 1; t < 512; t++) {
    float e_nx = (t < 511) ? emis[(size_t)(b * 512 + t + 1) * 32 + j] : 0.f;
    float mA = alpha;
    mA = fmaxf(mA, __shfl_xor(mA, 1, 32));
    mA = fmaxf(mA, __shfl_xor(mA, 2, 32));
    mA = fmaxf(mA, __shfl_xor(mA, 4, 32));
    mA = fmaxf(mA, __shfl_xor(mA, 8, 32));
    mA = fmaxf(mA, __shfl_xor(mA, 16, 32));
    float p = __expf(alpha - mA);
    float s0 = 0.f, s1 = 0.f, s2 = 0.f, s3 = 0.f;
    #pragma unroll
    for (int i = 0; i < 32; i += 4) {
      s0 = fmaf(__shfl(p, i, 32),     etr[i],     s0);
      s1 = fmaf(__shfl(p, i + 1, 32), etr[i + 1], s1);
      s2 = fmaf(__shfl(p, i + 2, 32), etr[i + 2], s2);
      s3 = fmaf(__shfl(p, i + 3, 32), etr[i + 3], s3);
    }
    alpha = __logf((s0 + s1) + (s2 + s3)) + mA + e_cur;
    e_cur = e_nx;
  }
  float z = alpha + cend[j];
  float m2 = z;
  #pragma unroll
  for (int off = 16; off > 0; off >>= 1) m2 = fmaxf(m2, __shfl_xor(m2, off, 32));
  float s2r = __expf(z - m2);
  #pragma unroll
  for (int off = 16; off > 0; off >>= 1) s2r += __shfl_xor(s2r, off, 32);
  if (tid == 0) perb[b] = sn - (__logf(s2r) + m2);
}

__global__ void final_kernel(const float* __restrict__ perb, float* __restrict__ out) {
  int tid = threadIdx.x;
  float s = perb[tid];
  #pragma unroll
  for (int off = 32; off > 0; off >>= 1) s += __shfl_xor(s, off, 64);
  if (tid == 0) out[0] = -s;
}

// ---------------- host launch ----------------
extern "C" void kernel_launch(void* const* d_in, const int* in_sizes, int n_in,
                              void* d_out, int out_size, void* d_ws, size_t ws_size,
                              hipStream_t stream) {
  (void)in_sizes; (void)n_in; (void)out_size;
  const int* datas = (const int*)d_in[0];
  const int* labels = (const int*)d_in[1];
  const float* emb = (const float*)d_in[2];
  const float* w_ih0 = (const float*)d_in[3];
  const float* w_ih1 = (const float*)d_in[4];
  const float* w_hh = (const float*)d_in[5];
  const float* b_ih = (const float*)d_in[6];
  const float* b_hh = (const float*)d_in[7];
  const float* w_out = (const float*)d_in[8];
  const float* b_out = (const float*)d_in[9];
  const float* cstart = (const float*)d_in[10];
  const float* cend = (const float*)d_in[11];
  const float* ctrans = (const float*)d_in[12];

  char* ws = (char*)d_ws;
  ushort_t* x_bf = (ushort_t*)(ws + OFF_A);        // phases 1-2 (first 32MB of A region)
  ushort_t* out1 = (ushort_t*)(ws + OFF_A);        // phases 3-4 (alias, full 64MB)
  ushort_t* out0 = (ushort_t*)(ws + OFF_OUT0);
  ushort_t* xA0 = (ushort_t*)(ws + OFF_XG);        // primary xg pair
  ushort_t* xA1 = (ushort_t*)(ws + OFF_XG + 16777216);
  ushort_t* xB0a = (ushort_t*)(ws + OFF_A + 33554432);  // layer-0 secondary pair (behind x_bf)
  ushort_t* xB0b = (ushort_t*)(ws + OFF_A + 50331648);
  ushort_t* xB1a = (ushort_t*)(ws + OFF_END);           // layer-1 secondary pair (guarded)
  ushort_t* xB1b = (ushort_t*)(ws + OFF_END + 16777216);
  bool big = ws_size >= OFF_END + 33554432ull;
  float* emis = (float*)(ws + OFF_XG);             // phase 4 (alias)
  ushort_t* wih0_bf = (ushort_t*)(ws + OFF_WIH0);
  ushort_t* wih1_bf = (ushort_t*)(ws + OFF_WIH1);
  float* bias = (float*)(ws + OFF_BIAS);
  ushort_t* wout_bf = (ushort_t*)(ws + OFF_WOUT);
  ushort_t* hc0 = (ushort_t*)(ws + OFF_HC);        // layer0: [2 dir][2 buf][32768]
  ushort_t* hc1 = hc0 + 131072;                    // layer1
  float* cst0 = (float*)(ws + OFF_CST);
  float* cst1 = cst0 + 65536;
  int* bar = (int*)(ws + OFF_BAR);                 // [2 layer][2 dir][32][4][16] ints
  float* perb = (float*)(ws + OFF_PERB);

  // zero h parity buffers, carry state, flags, perb
  hipMemsetAsync(ws + OFF_HC, 0, OFF_END - OFF_HC, stream);

  prep_embed<<<8192, 256, 0, stream>>>(datas, emb, x_bf, w_ih0, w_ih1, b_ih, b_hh, w_out,
                                       wih0_bf, wih1_bf, bias, wout_bf);

  // ---- layer 0 (A = x_bf, K=512): lstm(c) || gemm(c+1) fused ----
  gemm_chunk<<<1024, 256, 0, stream>>>(x_bf, 512, wih0_bf, bias, xA0, xA1, 0, 448);
  for (int c = 0; c < 8; c++) {
    ushort_t* r0 = (c & 1) ? xB0a : xA0;
    ushort_t* r1 = (c & 1) ? xB0b : xA1;
    if (c < 7) {
      ushort_t* w0 = ((c + 1) & 1) ? xB0a : xA0;
      ushort_t* w1 = ((c + 1) & 1) ? xB0b : xA1;
      fused_chunk<<<1088, 256, 0, stream>>>(r0, r1, w_hh, hc0, cst0, out0, bar, c,
                                            x_bf, 512, wih0_bf, bias, w0, w1,
                                            (c + 1) * 64, (6 - c) * 64);
    } else {
      lstm_chunk<<<64, 256, 0, stream>>>(r0, r1, w_hh, hc0, cst0, out0, bar, c);
    }
  }

  // ---- layer 1 (A = out0, K=1024) ----
  gemm_chunk<<<1024, 256, 0, stream>>>(out0, 1024, wih1_bf, bias + 4096, xA0, xA1, 0, 448);
  for (int c = 0; c < 8; c++) {
    if (big) {
      ushort_t* r0 = (c & 1) ? xB1a : xA0;
      ushort_t* r1 = (c & 1) ? xB1b : xA1;
      if (c < 7) {
        ushort_t* w0 = ((c + 1) & 1) ? xB1a : xA0;
        ushort_t* w1 = ((c + 1) & 1) ? xB1b : xA1;
        fused_chunk<<<1088, 256, 0, stream>>>(r0, r1, w_hh + 2097152, hc1, cst1, out1,
                                              bar + 4096, c,
                                              out0, 1024, wih1_bf, bias + 4096, w0, w1,
                                              (c + 1) * 64, (6 - c) * 64);
      } else {
        lstm_chunk<<<64, 256, 0, stream>>>(r0, r1, w_hh + 2097152, hc1, cst1, out1,
                                           bar + 4096, c);
      }
    } else {
      // serial fallback: single xg pair, gemm(c+1) after lstm(c)
      lstm_chunk<<<64, 256, 0, stream>>>(xA0, xA1, w_hh + 2097152, hc1, cst1, out1,
                                         bar + 4096, c);
      if (c < 7)
        gemm_chunk<<<1024, 256, 0, stream>>>(out0, 1024, wih1_bf, bias + 4096, xA0, xA1,
                                             (c + 1) * 64, (6 - c) * 64);
    }
  }

  // emissions + CRF
  emis_kernel<<<256, 256, 0, stream>>>(out1, wout_bf, b_out, emis);
  fwd_kernel<<<64, 64, 0, stream>>>(labels, emis, ctrans, cstart, cend, perb);
  final_kernel<<<1, 64, 0, stream>>>(perb, (float*)d_out);
}

// Round 7
// 4845.004 us; speedup vs baseline: 1.1522x; 1.1522x over previous
//
#include <hip/hip_runtime.h>

typedef unsigned short ushort_t;
typedef unsigned long long u64_t;
typedef __attribute__((ext_vector_type(8))) short short8;
typedef __attribute__((ext_vector_type(4))) float floatx4;

// Problem constants: V=50000, E=512, H=512, L=32, B=64, T=512
// Chunked: NC=8 chunks of CS=64 steps.

__device__ __forceinline__ float bf2f(ushort_t u) {
  unsigned x = ((unsigned)u) << 16;
  return __builtin_bit_cast(float, x);
}
__device__ __forceinline__ ushort_t f2bf(float f) {
  unsigned x = __builtin_bit_cast(unsigned, f);
  x += 0x7FFFu + ((x >> 16) & 1u);
  return (ushort_t)(x >> 16);
}
__device__ __forceinline__ float sigf(float x) { return 1.0f / (1.0f + __expf(-x)); }
__device__ __forceinline__ float tanhf_(float x) { return 1.0f - 2.0f / (__expf(2.0f * x) + 1.0f); }

// ---------------- workspace layout (bytes) ----------------
static const size_t OFF_A    = 0;            // x_bf [32768][512] bf16 (32MB) + xgB0 pair (32MB)
                                             // out1 [32768][1024] bf16 (phases 3-4)   67108864
static const size_t OFF_OUT0 = 67108864;     // out0 [32768][1024] bf16                      67108864
static const size_t OFF_XG   = 134217728;    // xgA pair [64][64][2048] bf16 each (33554432)
                                             // emis [32768][32] f32 aliases this in phase 4
static const size_t OFF_WIH0 = 167772160;    // wih0_bf [2][2048][512] bf16    4194304
static const size_t OFF_WIH1 = 171966464;    // wih1_bf [2][2048][1024] bf16   8388608
static const size_t OFF_BIAS = 180355072;    // bias [2][2][2048] f32          32768
static const size_t OFF_WOUT = 180387840;    // w_out frag-major bf16          65536
static const size_t OFF_HC   = 180453376;    // h exchange [2 layers][2 dir][2 buf][32768] bf16 frag-major
static const size_t OFF_CST  = 181501952;    // c state [2 layers][2 dir][64][512] f32        524288
static const size_t OFF_BAR  = 182026240;    // wave flags [2 layer][2 dir][32 g][4 w][16] int  32768
static const size_t OFF_NUM  = 182059008;    // (spare)                        256
static const size_t OFF_PERB = 182059264;    // perb[64] f32                   256
static const size_t OFF_WHH  = 182059520;    // whh_pp [2 layer][2 dir][32 g][4096][8] bf16  8388608 (gated)
static const size_t OFF_XB1  = 190448128;    // xgB1 pair (33554432, gated)
// pp_ok:  ws_size >= OFF_WHH + 8388608
// big:    ws_size >= OFF_XB1 + 33554432

// ---------------- prep + embed fused ----------------
__global__ void prep_embed(const int* __restrict__ datas, const float* __restrict__ emb,
                           ushort_t* __restrict__ x_bf,
                           const float* __restrict__ w_ih0, const float* __restrict__ w_ih1,
                           const float* __restrict__ b_ih, const float* __restrict__ b_hh,
                           const float* __restrict__ w_out, const float* __restrict__ w_hh,
                           ushort_t* __restrict__ wih0_bf, ushort_t* __restrict__ wih1_bf,
                           float* __restrict__ bias, ushort_t* __restrict__ wout_bf,
                           ushort_t* __restrict__ whh_pp, int do_pp) {
  int idx = blockIdx.x * 256 + threadIdx.x;
  int stride = gridDim.x * 256;
  // embedding gather + cast (2097152 = 32768 rows * 64 subs)
  for (int i = idx; i < 2097152; i += stride) {
    int row = i >> 6, sub = i & 63;
    int tok = datas[row];
    const float4* ep = (const float4*)(emb + (size_t)tok * 512 + sub * 8);
    float4 f0 = ep[0], f1 = ep[1];
    short8 v;
    v[0] = (short)f2bf(f0.x); v[1] = (short)f2bf(f0.y);
    v[2] = (short)f2bf(f0.z); v[3] = (short)f2bf(f0.w);
    v[4] = (short)f2bf(f1.x); v[5] = (short)f2bf(f1.y);
    v[6] = (short)f2bf(f1.z); v[7] = (short)f2bf(f1.w);
    *(short8*)(x_bf + (size_t)row * 512 + sub * 8) = v;
  }
  for (int i = idx; i < 2097152; i += stride) wih0_bf[i] = f2bf(w_ih0[i]);
  for (int i = idx; i < 4194304; i += stride) wih1_bf[i] = f2bf(w_ih1[i]);
  for (int i = idx; i < 8192; i += stride) bias[i] = b_ih[i] + b_hh[i];
  // w_out [1024][32] -> 16x16x32 B-operand frag-major
  for (int i = idx; i < 32768; i += stride) {
    int j = i & 7, Ls = (i >> 3) & 63, kb = (i >> 9) & 31, nt = i >> 14;
    int n = nt * 16 + (Ls & 15);
    int k = kb * 32 + ((Ls >> 4) & 3) * 8 + j;
    wout_bf[i] = f2bf(w_out[k * 32 + n]);
  }
  // w_hh -> per-(layer,dir,g) frag-major bf16 so the lstm preamble is a LINEAR 64KB copy.
  // pp[l][d][g][slot][j] = bf16(w_hh[l][d][gcol][k+j]),
  //   slot: q=slot>>10, kb=(slot>>6)&15, Ls=slot&63;
  //   gcol = q*512 + g*16 + (Ls&15);  k = kb*32 + ((Ls>>4)&3)*8
  if (do_pp) {
    for (int i = idx; i < 4194304; i += stride) {
      int j = i & 7, slot = (i >> 3) & 4095, g = (i >> 15) & 31, d = (i >> 20) & 1, l = i >> 21;
      int q = slot >> 10, kb = (slot >> 6) & 15, Ls = slot & 63;
      int gcol = q * 512 + g * 16 + (Ls & 15);
      int k = kb * 32 + ((Ls >> 4) & 3) * 8 + j;
      whh_pp[i] = f2bf(w_hh[(((size_t)(l * 2 + d) * 2048) + gcol) * 512 + k]);
    }
  }
}

// ---------------- GEMM body (chunked input-projection) ----------------
__device__ __forceinline__ void gemm_body(ushort_t* alds, ushort_t* blds, int gid, int tid,
                                          const ushort_t* __restrict__ A, int K,
                                          const ushort_t* __restrict__ W,
                                          const float* __restrict__ biasL,
                                          ushort_t* __restrict__ xg0,
                                          ushort_t* __restrict__ xg1,
                                          int t00, int t01) {
  int dir = gid >> 9, r = gid & 511;
  int mt = r & 31, ntt = r >> 5;
  int t0 = dir ? t01 : t00;
  const ushort_t* Bm = W + (size_t)dir * 2048 * K;
  const float* bptr = biasL + dir * 2048;
  ushort_t* xg = dir ? xg1 : xg0;
  int bm0 = mt * 128, bn0 = ntt * 128;
  int L = tid & 63, w = tid >> 6;
  int wm = w & 1, wn = w >> 1;
  floatx4 acc[4][4] = {};
  for (int k0 = 0; k0 < K; k0 += 32) {
    __syncthreads();
    #pragma unroll
    for (int rep = 0; rep < 2; rep++) {
      int slot = rep * 256 + tid;  // 0..511
      int t8 = slot >> 6, Ls = slot & 63;
      int col = k0 + (Ls >> 4) * 8;
      int mp = bm0 + t8 * 16 + (Ls & 15);                 // m' in [0,4096)
      int Arow = (mp >> 6) * 512 + t0 + (mp & 63);        // b*512 + t
      *(short8*)&alds[slot * 8] = *(const short8*)&A[(size_t)Arow * K + col];
      int rowb = bn0 + t8 * 16 + (Ls & 15);               // gate col in [0,2048)
      *(short8*)&blds[slot * 8] = *(const short8*)&Bm[(size_t)rowb * K + col];
    }
    __syncthreads();
    short8 af[4];
    #pragma unroll
    for (int a = 0; a < 4; a++) af[a] = *(const short8*)&alds[((wm * 4 + a) * 64 + L) * 8];
    #pragma unroll
    for (int bq = 0; bq < 4; bq++) {
      short8 bfr = *(const short8*)&blds[((wn * 4 + bq) * 64 + L) * 8];
      #pragma unroll
      for (int a = 0; a < 4; a++)
        acc[a][bq] = __builtin_amdgcn_mfma_f32_16x16x32_bf16(af[a], bfr, acc[a][bq], 0, 0, 0);
    }
  }
  int lm = L >> 4, ln = L & 15;
  #pragma unroll
  for (int bq = 0; bq < 4; bq++) {
    int n = bn0 + (wn * 4 + bq) * 16 + ln;  // [0,2048)
    float bv = bptr[n];
    #pragma unroll
    for (int a = 0; a < 4; a++) {
      #pragma unroll
      for (int rr = 0; rr < 4; rr++) {
        int m = bm0 + (wm * 4 + a) * 16 + lm * 4 + rr;
        int b = m >> 6, ts = m & 63;
        xg[((size_t)(ts * 64 + b)) * 2048 + n] = f2bf(acc[a][bq][rr] + bv);
      }
    }
  }
}

__global__ __launch_bounds__(256) void gemm_chunk(const ushort_t* __restrict__ A, int K,
                                                  const ushort_t* __restrict__ W,
                                                  const float* __restrict__ biasL,
                                                  ushort_t* __restrict__ xg0c,
                                                  ushort_t* __restrict__ xg1c,
                                                  int t00, int t01) {
  __shared__ alignas(16) ushort_t alds[512 * 8];
  __shared__ alignas(16) ushort_t blds[512 * 8];
  gemm_body(alds, blds, blockIdx.x, threadIdx.x, A, K, W, biasL, xg0c, xg1c, t00, t01);
}

// ---------------- LSTM body: one chunk of 64 steps (proven R1/R2 protocol) ----------------
// block bid in [0,64): dir d = bid>>5, slice g = bid&31 owns h-cols [g*16,g*16+16).
// h exchanged frag-major at AGENT scope; per-WAVE sync planes. Per-step protocol:
//   h stores -> s_waitcnt vmcnt(0) (per-wave) -> lane0 posts wave-flag -> out/xg prefetch
//   fill the poll window -> poll the 32 same-plane wave-flags (lanes 0..31, ballot).
__device__ __forceinline__ void lstm_body(ushort_t* wlds, int bid, int tid,
                                          const ushort_t* __restrict__ xg0c,
                                          const ushort_t* __restrict__ xg1c,
                                          const float* __restrict__ whh_f,   // layer base [2][2048][512] f32
                                          const ushort_t* __restrict__ whh_pp, // layer base pre-permuted (or null)
                                          ushort_t* __restrict__ hcL,       // [2 dir][2 buf][32768]
                                          float* __restrict__ cstL,         // [2 dir][64][512]
                                          ushort_t* __restrict__ outL,      // [32768][1024], col offset d*512
                                          int* __restrict__ barF, int c) {
  int d = bid >> 5, g = bid & 31, j0 = g * 16;
  int L = tid & 63, w = tid >> 6;
  if (whh_pp) {
    // preamble = linear 64KB bf16 copy (pre-permuted in prep)
    const ushort_t* src = whh_pp + (size_t)(d * 32 + g) * 32768;
    #pragma unroll
    for (int it = 0; it < 16; it++) {
      int slot = it * 256 + tid;
      *(short8*)&wlds[slot * 8] = *(const short8*)&src[slot * 8];
    }
  } else {
    const float* wptr = whh_f + (size_t)d * 2048 * 512;
    #pragma unroll
    for (int it = 0; it < 16; it++) {
      int slot = it * 256 + tid;  // 0..4095
      int q = slot >> 10, kb = (slot >> 6) & 15, Ls = slot & 63;
      int gcol = q * 512 + j0 + (Ls & 15);
      int k = kb * 32 + (Ls >> 4) * 8;
      const float* src = wptr + (size_t)gcol * 512 + k;
      float4 f0 = *(const float4*)src;
      float4 f1 = *(const float4*)(src + 4);
      short8 v;
      v[0] = (short)f2bf(f0.x); v[1] = (short)f2bf(f0.y);
      v[2] = (short)f2bf(f0.z); v[3] = (short)f2bf(f0.w);
      v[4] = (short)f2bf(f1.x); v[5] = (short)f2bf(f1.y);
      v[6] = (short)f2bf(f1.z); v[7] = (short)f2bf(f1.w);
      *(short8*)&wlds[slot * 8] = v;
    }
  }
  __syncthreads();
  const ushort_t* xgd = d ? xg1c : xg0c;
  ushort_t* hcd = hcL + (size_t)d * 2 * 32768;     // [2 parity][32768]
  int* flg = barF + d * 2048;                      // [32 g][4 w][16] ints (64B spacing)
  int* myflag = flg + (g * 4 + w) * 16;
  const int* pollp = flg + ((L & 31) * 4 + w) * 16;  // lane L<32 polls block L, wave w
  bool pact = (L < 32);
  int q8 = L >> 4, jj = L & 15;
  int mbase = w * 16 + q8 * 4;                  // C-layout batch-row base
  // writer slot (even-jj lanes store packed dwords for cols jj, jj+1):
  int wslot = ((w * 16 + (g >> 1)) * 64 + q8 * 4 + 16 * ((g & 1) * 2 + (jj >> 3))) * 8 + (jj & 7);
  // reader base: wave w, lane L, kb: 16B at ushort index rbase + kb*512
  int rbase = (w * 16 * 64 + L) * 8;
  float cv[4];
  #pragma unroll
  for (int rr = 0; rr < 4; rr++) cv[rr] = cstL[(size_t)d * 32768 + (mbase + rr) * 512 + j0 + jj];

  auto ldxg = [&](int sl2, ushort_t dst[4][4]) {
    int ts2 = d ? (63 - sl2) : sl2;
    #pragma unroll
    for (int rr = 0; rr < 4; rr++) {
      const ushort_t* xrow = xgd + ((size_t)(ts2 * 64 + mbase + rr)) * 2048 + j0 + jj;
      #pragma unroll
      for (int q = 0; q < 4; q++) dst[q][rr] = xrow[q * 512];
    }
  };

  ushort_t xgu[4][4];
  ldxg(0, xgu);

  for (int sl = 0; sl < 64; sl++) {
    int s = c * 64 + sl;
    int t = d ? (511 - s) : s;
    const u64_t* h64 = (const u64_t*)(hcd + (size_t)(s & 1) * 32768);
    unsigned* h32w = (unsigned*)(hcd + (size_t)((s + 1) & 1) * 32768);
    // ---- issue ALL h loads upfront (32 independent agent-scope u64 loads) ----
    int b64 = rbase >> 2;  // u64 index; kb adds 128
    u64_t hv[32];
    #pragma unroll
    for (int kb = 0; kb < 16; kb++) {
      hv[2 * kb]     = __hip_atomic_load(h64 + b64 + kb * 128,     __ATOMIC_RELAXED, __HIP_MEMORY_SCOPE_AGENT);
      hv[2 * kb + 1] = __hip_atomic_load(h64 + b64 + kb * 128 + 1, __ATOMIC_RELAXED, __HIP_MEMORY_SCOPE_AGENT);
    }
    floatx4 acc[4] = {};
    #pragma unroll
    for (int kb = 0; kb < 16; kb++) {
      union { u64_t u[2]; short8 v; } pk;
      pk.u[0] = hv[2 * kb];
      pk.u[1] = hv[2 * kb + 1];
      short8 a = pk.v;
      #pragma unroll
      for (int q = 0; q < 4; q++) {
        short8 bfr = *(const short8*)&wlds[((q * 16 + kb) * 64 + L) * 8];
        acc[q] = __builtin_amdgcn_mfma_f32_16x16x32_bf16(a, bfr, acc[q], 0, 0, 0);
      }
    }
    // ---- pointwise LSTM cell ----
    ushort_t hbv[4];
    #pragma unroll
    for (int rr = 0; rr < 4; rr++) {
      float ii = acc[0][rr] + bf2f(xgu[0][rr]);
      float ff = acc[1][rr] + bf2f(xgu[1][rr]);
      float gg = acc[2][rr] + bf2f(xgu[2][rr]);
      float oo = acc[3][rr] + bf2f(xgu[3][rr]);
      float cc = sigf(ff) * cv[rr] + sigf(ii) * tanhf_(gg);
      cv[rr] = cc;
      hbv[rr] = f2bf(sigf(oo) * tanhf_(cc));
    }
    // ---- pack column pairs (jj, jj^1) into dwords; even-jj lanes store h ONLY ----
    bool evn = (jj & 1) == 0;
    unsigned pk4[4];
    #pragma unroll
    for (int rr = 0; rr < 4; rr++) {
      unsigned mine = (unsigned)hbv[rr];
      unsigned nb = (unsigned)__shfl_xor((int)mine, 1, 64);
      pk4[rr] = mine | (nb << 16);
      if (evn)
        __hip_atomic_store(h32w + ((wslot + rr * 8) >> 1), pk4[rr],
                           __ATOMIC_RELAXED, __HIP_MEMORY_SCOPE_AGENT);
    }
    if (sl != 63) {
      // drain this wave's h stores (and retire its h loads) — per-wave counter
      asm volatile("s_waitcnt vmcnt(0)" ::: "memory");
      if (L == 0)
        __hip_atomic_store(myflag, s + 1, __ATOMIC_RELAXED, __HIP_MEMORY_SCOPE_AGENT);
      // ---- fill the poll window: out1 stores + next-step xg prefetch ----
      if (evn) {
        #pragma unroll
        for (int rr = 0; rr < 4; rr++) {
          int m = mbase + rr;
          *(unsigned*)&outL[((size_t)m * 512 + t) * 1024 + (d << 9) + j0 + jj] = pk4[rr];
        }
      }
      ldxg(sl + 1, xgu);
      int target = s + 1, guard = 0;
      while (guard < (1 << 17)) {
        int f = pact ? __hip_atomic_load(pollp, __ATOMIC_RELAXED, __HIP_MEMORY_SCOPE_AGENT)
                     : target;
        if (__ballot(f >= target) == ~0ULL) break;
        guard++;
      }
    } else {
      if (evn) {
        #pragma unroll
        for (int rr = 0; rr < 4; rr++) {
          int m = mbase + rr;
          *(unsigned*)&outL[((size_t)m * 512 + t) * 1024 + (d << 9) + j0 + jj] = pk4[rr];
        }
      }
    }
  }
  #pragma unroll
  for (int rr = 0; rr < 4; rr++) cstL[(size_t)d * 32768 + (mbase + rr) * 512 + j0 + jj] = cv[rr];
}

__global__ __launch_bounds__(256) void lstm_chunk(const ushort_t* __restrict__ xg0c,
                                                  const ushort_t* __restrict__ xg1c,
                                                  const float* __restrict__ whh_f,
                                                  const ushort_t* __restrict__ whh_pp,
                                                  ushort_t* __restrict__ hcL,
                                                  float* __restrict__ cstL,
                                                  ushort_t* __restrict__ outL,
                                                  int* __restrict__ barF, int c) {
  __shared__ alignas(16) ushort_t wlds[32768];  // 64 KB
  lstm_body(wlds, blockIdx.x, threadIdx.x, xg0c, xg1c, whh_f, whh_pp, hcL, cstL, outL, barF, c);
}

// ---------------- fused dispatch: lstm(c) on blocks 0..63  ||  gemm(c+1) on blocks 64..1087 ----
__global__ __launch_bounds__(256) void fused_chunk(
    // lstm(c) args
    const ushort_t* __restrict__ l_xg0, const ushort_t* __restrict__ l_xg1,
    const float* __restrict__ whh_f, const ushort_t* __restrict__ whh_pp,
    ushort_t* __restrict__ hcL,
    float* __restrict__ cstL, ushort_t* __restrict__ outL,
    int* __restrict__ barF, int c,
    // gemm(c+1) args
    const ushort_t* __restrict__ g_A, int g_K,
    const ushort_t* __restrict__ g_W, const float* __restrict__ g_bias,
    ushort_t* __restrict__ g_xg0, ushort_t* __restrict__ g_xg1,
    int g_t00, int g_t01) {
  __shared__ alignas(16) ushort_t lds[32768];  // 64 KB, unioned
  if (blockIdx.x < 64) {
    lstm_body(lds, blockIdx.x, threadIdx.x, l_xg0, l_xg1, whh_f, whh_pp, hcL, cstL, outL, barF, c);
  } else {
    gemm_body(lds, lds + 4096, blockIdx.x - 64, threadIdx.x,
              g_A, g_K, g_W, g_bias, g_xg0, g_xg1, g_t00, g_t01);
  }
}

// ---------------- emissions: [32768,1024] @ [1024,32] + b_out ----------------
__global__ __launch_bounds__(256) void emis_kernel(const ushort_t* __restrict__ out1,
                                                   const ushort_t* __restrict__ wout_bf,
                                                   const float* __restrict__ b_out,
                                                   float* __restrict__ emis) {
  int tid = threadIdx.x, L = tid & 63, w = tid >> 6;
  int bm0 = blockIdx.x * 128;
  int q8 = L >> 4, ln = L & 15;
  floatx4 acc[2][2] = {};
  #pragma unroll 4
  for (int kb = 0; kb < 32; kb++) {
    short8 a0 = *(const short8*)&out1[(size_t)(bm0 + (w * 2 + 0) * 16 + ln) * 1024 + kb * 32 + q8 * 8];
    short8 a1 = *(const short8*)&out1[(size_t)(bm0 + (w * 2 + 1) * 16 + ln) * 1024 + kb * 32 + q8 * 8];
    #pragma unroll
    for (int nt = 0; nt < 2; nt++) {
      short8 bfr = *(const short8*)&wout_bf[((size_t)(nt * 32 + kb) * 64 + L) * 8];
      acc[0][nt] = __builtin_amdgcn_mfma_f32_16x16x32_bf16(a0, bfr, acc[0][nt], 0, 0, 0);
      acc[1][nt] = __builtin_amdgcn_mfma_f32_16x16x32_bf16(a1, bfr, acc[1][nt], 0, 0, 0);
    }
  }
  #pragma unroll
  for (int mt = 0; mt < 2; mt++) {
    #pragma unroll
    for (int nt = 0; nt < 2; nt++) {
      int n = nt * 16 + ln;
      float bv = b_out[n];
      #pragma unroll
      for (int rr = 0; rr < 4; rr++) {
        int m = bm0 + (w * 2 + mt) * 16 + q8 * 4 + rr;
        emis[(size_t)m * 32 + n] = acc[mt][nt][rr] + bv;
      }
    }
  }
}

// ---------------- CRF forward scan (numerator folded in) ----------------
__global__ __launch_bounds__(64) void fwd_kernel(const int* __restrict__ labels,
                                                 const float* __restrict__ emis,
                                                 const float* __restrict__ trans,
                                                 const float* __restrict__ cstart,
                                                 const float* __restrict__ cend,
                                                 float* __restrict__ perb) {
  int b = blockIdx.x, tid = threadIdx.x, j = tid & 31;
  // numerator (butterfly reduce -> all lanes hold the sum)
  float sn = 0.f;
  for (int t = tid; t < 512; t += 64) {
    int tag = labels[b * 512 + t];
    sn += emis[(size_t)(b * 512 + t) * 32 + tag];
    if (t < 511) sn += trans[tag * 32 + labels[b * 512 + t + 1]];
  }
  #pragma unroll
  for (int off = 32; off > 0; off >>= 1) sn += __shfl_xor(sn, off, 64);
  sn += cstart[labels[b * 512]] + cend[labels[b * 512 + 511]];
  // forward scan
  float etr[32];
  #pragma unroll
  for (int i = 0; i < 32; i++) etr[i] = __expf(trans[i * 32 + j]);
  float alpha = cstart[j] + emis[(size_t)(b * 512) * 32 + j];
  float e_cur = emis[(size_t)(b * 512 + 1) * 32 + j];
  for (int t = 1; t < 512; t++) {
    float e_nx = (t < 511) ? emis[(size_t)(b * 512 + t + 1) * 32 + j] : 0.f;
    float mA = alpha;
    mA = fmaxf(mA, __shfl_xor(mA, 1, 32));
    mA = fmaxf(mA, __shfl_xor(mA, 2, 32));
    mA = fmaxf(mA, __shfl_xor(mA, 4, 32));
    mA = fmaxf(mA, __shfl_xor(mA, 8, 32));
    mA = fmaxf(mA, __shfl_xor(mA, 16, 32));
    float p = __expf(alpha - mA);
    float s0 = 0.f, s1 = 0.f, s2 = 0.f, s3 = 0.f;
    #pragma unroll
    for (int i = 0; i < 32; i += 4) {
      s0 = fmaf(__shfl(p, i, 32),     etr[i],     s0);
      s1 = fmaf(__shfl(p, i + 1, 32), etr[i + 1], s1);
      s2 = fmaf(__shfl(p, i + 2, 32), etr[i + 2], s2);
      s3 = fmaf(__shfl(p, i + 3, 32), etr[i + 3], s3);
    }
    alpha = __logf((s0 + s1) + (s2 + s3)) + mA + e_cur;
    e_cur = e_nx;
  }
  float z = alpha + cend[j];
  float m2 = z;
  #pragma unroll
  for (int off = 16; off > 0; off >>= 1) m2 = fmaxf(m2, __shfl_xor(m2, off, 32));
  float s2r = __expf(z - m2);
  #pragma unroll
  for (int off = 16; off > 0; off >>= 1) s2r += __shfl_xor(s2r, off, 32);
  if (tid == 0) perb[b] = sn - (__logf(s2r) + m2);
}

__global__ void final_kernel(const float* __restrict__ perb, float* __restrict__ out) {
  int tid = threadIdx.x;
  float s = perb[tid];
  #pragma unroll
  for (int off = 32; off > 0; off >>= 1) s += __shfl_xor(s, off, 64);
  if (tid == 0) out[0] = -s;
}

// ---------------- host launch ----------------
extern "C" void kernel_launch(void* const* d_in, const int* in_sizes, int n_in,
                              void* d_out, int out_size, void* d_ws, size_t ws_size,
                              hipStream_t stream) {
  (void)in_sizes; (void)n_in; (void)out_size;
  const int* datas = (const int*)d_in[0];
  const int* labels = (const int*)d_in[1];
  const float* emb = (const float*)d_in[2];
  const float* w_ih0 = (const float*)d_in[3];
  const float* w_ih1 = (const float*)d_in[4];
  const float* w_hh = (const float*)d_in[5];
  const float* b_ih = (const float*)d_in[6];
  const float* b_hh = (const float*)d_in[7];
  const float* w_out = (const float*)d_in[8];
  const float* b_out = (const float*)d_in[9];
  const float* cstart = (const float*)d_in[10];
  const float* cend = (const float*)d_in[11];
  const float* ctrans = (const float*)d_in[12];

  char* ws = (char*)d_ws;
  ushort_t* x_bf = (ushort_t*)(ws + OFF_A);        // phases 1-2 (first 32MB of A region)
  ushort_t* out1 = (ushort_t*)(ws + OFF_A);        // phases 3-4 (alias, full 64MB)
  ushort_t* out0 = (ushort_t*)(ws + OFF_OUT0);
  ushort_t* xA0 = (ushort_t*)(ws + OFF_XG);        // primary xg pair
  ushort_t* xA1 = (ushort_t*)(ws + OFF_XG + 16777216);
  ushort_t* xB0a = (ushort_t*)(ws + OFF_A + 33554432);  // layer-0 secondary pair (behind x_bf)
  ushort_t* xB0b = (ushort_t*)(ws + OFF_A + 50331648);
  ushort_t* xB1a = (ushort_t*)(ws + OFF_XB1);           // layer-1 secondary pair (guarded)
  ushort_t* xB1b = (ushort_t*)(ws + OFF_XB1 + 16777216);
  bool pp_ok = ws_size >= OFF_WHH + 8388608ull;
  bool big = ws_size >= OFF_XB1 + 33554432ull;
  float* emis = (float*)(ws + OFF_XG);             // phase 4 (alias)
  ushort_t* wih0_bf = (ushort_t*)(ws + OFF_WIH0);
  ushort_t* wih1_bf = (ushort_t*)(ws + OFF_WIH1);
  float* bias = (float*)(ws + OFF_BIAS);
  ushort_t* wout_bf = (ushort_t*)(ws + OFF_WOUT);
  ushort_t* hc0 = (ushort_t*)(ws + OFF_HC);        // layer0: [2 dir][2 buf][32768]
  ushort_t* hc1 = hc0 + 131072;                    // layer1
  float* cst0 = (float*)(ws + OFF_CST);
  float* cst1 = cst0 + 65536;
  int* bar = (int*)(ws + OFF_BAR);                 // [2 layer][2 dir][32][4][16] ints
  float* perb = (float*)(ws + OFF_PERB);
  ushort_t* whh_pp = pp_ok ? (ushort_t*)(ws + OFF_WHH) : (ushort_t*)nullptr;
  ushort_t* pp0 = pp_ok ? whh_pp : (ushort_t*)nullptr;            // layer-0 base
  ushort_t* pp1 = pp_ok ? (whh_pp + 2097152) : (ushort_t*)nullptr; // layer-1 base

  // zero h parity buffers, carry state, flags, perb
  hipMemsetAsync(ws + OFF_HC, 0, OFF_WHH - OFF_HC, stream);

  prep_embed<<<8192, 256, 0, stream>>>(datas, emb, x_bf, w_ih0, w_ih1, b_ih, b_hh, w_out,
                                       w_hh, wih0_bf, wih1_bf, bias, wout_bf,
                                       whh_pp, pp_ok ? 1 : 0);

  // ---- layer 0 (A = x_bf, K=512): lstm(c) || gemm(c+1) fused ----
  gemm_chunk<<<1024, 256, 0, stream>>>(x_bf, 512, wih0_bf, bias, xA0, xA1, 0, 448);
  for (int c = 0; c < 8; c++) {
    ushort_t* r0 = (c & 1) ? xB0a : xA0;
    ushort_t* r1 = (c & 1) ? xB0b : xA1;
    if (c < 7) {
      ushort_t* w0 = ((c + 1) & 1) ? xB0a : xA0;
      ushort_t* w1 = ((c + 1) & 1) ? xB0b : xA1;
      fused_chunk<<<1088, 256, 0, stream>>>(r0, r1, w_hh, pp0, hc0, cst0, out0, bar, c,
                                            x_bf, 512, wih0_bf, bias, w0, w1,
                                            (c + 1) * 64, (6 - c) * 64);
    } else {
      lstm_chunk<<<64, 256, 0, stream>>>(r0, r1, w_hh, pp0, hc0, cst0, out0, bar, c);
    }
  }

  // ---- layer 1 (A = out0, K=1024) ----
  gemm_chunk<<<1024, 256, 0, stream>>>(out0, 1024, wih1_bf, bias + 4096, xA0, xA1, 0, 448);
  for (int c = 0; c < 8; c++) {
    if (big) {
      ushort_t* r0 = (c & 1) ? xB1a : xA0;
      ushort_t* r1 = (c & 1) ? xB1b : xA1;
      if (c < 7) {
        ushort_t* w0 = ((c + 1) & 1) ? xB1a : xA0;
        ushort_t* w1 = ((c + 1) & 1) ? xB1b : xA1;
        fused_chunk<<<1088, 256, 0, stream>>>(r0, r1, w_hh + 2097152, pp1, hc1, cst1, out1,
                                              bar + 4096, c,
                                              out0, 1024, wih1_bf, bias + 4096, w0, w1,
                                              (c + 1) * 64, (6 - c) * 64);
      } else {
        lstm_chunk<<<64, 256, 0, stream>>>(r0, r1, w_hh + 2097152, pp1, hc1, cst1, out1,
                                           bar + 4096, c);
      }
    } else {
      // serial fallback: single xg pair, gemm(c+1) after lstm(c)
      lstm_chunk<<<64, 256, 0, stream>>>(xA0, xA1, w_hh + 2097152, pp1, hc1, cst1, out1,
                                         bar + 4096, c);
      if (c < 7)
        gemm_chunk<<<1024, 256, 0, stream>>>(out0, 1024, wih1_bf, bias + 4096, xA0, xA1,
                                             (c + 1) * 64, (6 - c) * 64);
    }
  }

  // emissions + CRF
  emis_kernel<<<256, 256, 0, stream>>>(out1, wout_bf, b_out, emis);
  fwd_kernel<<<64, 64, 0, stream>>>(labels, emis, ctrans, cstart, cend, perb);
  final_kernel<<<1, 64, 0, stream>>>(perb, (float*)d_out);
}